// Round 4
// baseline (359.473 us; speedup 1.0000x reference)
//
#include <hip/hip_runtime.h>

#define B_  4
#define N_  131072
#define J_  55
#define JP_ 56        // padded J (pad entries are zero)
#define D_  64
#define D3_ 262144    // 64^3
#define PF_ 486
#define COLS_ 31425   // M*3

// prelude zone sizes (blocks)
#define GZ_ 1024      // G-blend zone: D3_/256
#define OZ_ 123       // off_pose zone: one block per 256 cols, full depth

#define BL16(u) __uint_as_float((u) << 16)
#define BH16(u) __uint_as_float((u) & 0xffff0000u)

// 16B vector with only 4B alignment guarantee (lbsw rows are 220B apart)
typedef float f4a __attribute__((ext_vector_type(4), aligned(4)));

__device__ __forceinline__ unsigned short f2bf(float v) {
    unsigned u = __float_as_uint(v);
    u += 0x7fffu + ((u >> 16) & 1u);   // round-to-nearest-even
    return (unsigned short)(u >> 16);
}

// ---------------- tfs = A @ A_inv, padded to JP_ joints --------------------
__global__ __launch_bounds__(256) void k_tfs(const float* __restrict__ A,
                                             const float* __restrict__ Ainv,
                                             float* __restrict__ tfsP) {
    int tid = blockIdx.x * 256 + threadIdx.x;
    if (tid >= B_ * JP_ * 16) return;
    int rc = tid & 15;
    int jb = tid >> 4;
    int j = jb % JP_;
    int b = jb / JP_;
    float v = 0.f;
    if (j < J_) {
        int r = rc >> 2, c = rc & 3;
#pragma unroll
        for (int k = 0; k < 4; ++k)
            v += A[((b * J_ + j) * 4 + r) * 4 + k] * Ainv[(j * 4 + k) * 4 + c];
    }
    tfsP[tid] = v;
}

// ------ k_prelude: two independent zones overlap on the GPU ----------------
// zone G  [0, GZ_):        G[b][v][16] bf16 + S[v] f32 (trilerp linearity)
// zone O  [GZ_, GZ_+OZ_):  off_full = betas@spdir + pf@podir (plain stores)
__global__ __launch_bounds__(256) void k_prelude(
    const float* __restrict__ vox, const float* __restrict__ tfsP,
    uint4* __restrict__ Gtb, float* __restrict__ Stb,
    const float* __restrict__ pf, const float* __restrict__ podir,
    const float* __restrict__ betas, const float* __restrict__ spdir,
    float* __restrict__ off_full) {
    int bx = blockIdx.x;
    int tid = threadIdx.x;

    if (bx < GZ_) {
        // ---- G zone: all 55 vox loads issued upfront (one vmcnt chain)
        int v = bx * 256 + tid;
        float wv[J_];
#pragma unroll
        for (int j = 0; j < J_; ++j) wv[j] = vox[(size_t)j * D3_ + v];
        float g[4][16];
        float s = 0.f;
#pragma unroll
        for (int b = 0; b < 4; ++b)
#pragma unroll
            for (int r = 0; r < 16; ++r) g[b][r] = 0.f;
#pragma unroll
        for (int j = 0; j < J_; ++j) {
            float w = wv[j];
            s += w;
#pragma unroll
            for (int b = 0; b < 4; ++b) {
                const float* tr = tfsP + (b * JP_ + j) * 16;  // s_load
#pragma unroll
                for (int r = 0; r < 16; ++r) g[b][r] += w * tr[r];
            }
        }
        Stb[v] = s;
#pragma unroll
        for (int b = 0; b < 4; ++b) {
            unsigned gw[8];
#pragma unroll
            for (int k = 0; k < 8; ++k)
                gw[k] = (unsigned)f2bf(g[b][2 * k]) |
                        ((unsigned)f2bf(g[b][2 * k + 1]) << 16);
            uint4* gp = Gtb + ((size_t)b * D3_ + v) * 2;
            gp[0] = make_uint4(gw[0], gw[1], gw[2], gw[3]);
            gp[1] = make_uint4(gw[4], gw[5], gw[6], gw[7]);
        }
    } else {
        // ---- off_pose zone: full 486 depth, 16 loads in flight, no atomics
        int col = (bx - GZ_) * 256 + tid;
        if (col >= COLS_) return;
        float a0 = 0.f, a1 = 0.f, a2 = 0.f, a3 = 0.f;
        {   // shape blend term
            float sp[10];
#pragma unroll
            for (int l = 0; l < 10; ++l) sp[l] = spdir[col * 10 + l];
#pragma unroll
            for (int l = 0; l < 10; ++l) {
                a0 += betas[0 * 10 + l] * sp[l];
                a1 += betas[1 * 10 + l] * sp[l];
                a2 += betas[2 * 10 + l] * sp[l];
                a3 += betas[3 * 10 + l] * sp[l];
            }
        }
        int p = 0;
        for (; p + 16 <= PF_; p += 16) {
            float v16[16];
#pragma unroll
            for (int k = 0; k < 16; ++k)
                v16[k] = podir[(size_t)(p + k) * COLS_ + col];
#pragma unroll
            for (int k = 0; k < 16; ++k) {
                a0 += pf[0 * PF_ + p + k] * v16[k];
                a1 += pf[1 * PF_ + p + k] * v16[k];
                a2 += pf[2 * PF_ + p + k] * v16[k];
                a3 += pf[3 * PF_ + p + k] * v16[k];
            }
        }
        for (; p < PF_; ++p) {         // tail 486 - 480 = 6
            float v = podir[(size_t)p * COLS_ + col];
            a0 += pf[0 * PF_ + p] * v;
            a1 += pf[1 * PF_ + p] * v;
            a2 += pf[2 * PF_ + p] * v;
            a3 += pf[3 * PF_ + p] * v;
        }
        off_full[0 * COLS_ + col] = a0;
        off_full[1 * COLS_ + col] = a1;
        off_full[2 * COLS_ + col] = a2;
        off_full[3 * COLS_ + col] = a3;
    }
}

// accumulate 8 T-entries from two adjacent-corner G rows (bf16-packed)
#define ACC8(Toff, qa, qb)                                 \
    T[Toff + 0] += w0 * BL16(qa.x) + w1 * BL16(qb.x);      \
    T[Toff + 1] += w0 * BH16(qa.x) + w1 * BH16(qb.x);      \
    T[Toff + 2] += w0 * BL16(qa.y) + w1 * BL16(qb.y);      \
    T[Toff + 3] += w0 * BH16(qa.y) + w1 * BH16(qb.y);      \
    T[Toff + 4] += w0 * BL16(qa.z) + w1 * BL16(qb.z);      \
    T[Toff + 5] += w0 * BH16(qa.z) + w1 * BH16(qb.z);      \
    T[Toff + 6] += w0 * BL16(qa.w) + w1 * BL16(qb.w);      \
    T[Toff + 7] += w0 * BH16(qa.w) + w1 * BH16(qb.w);

// ------- fused main pass: compaction; regular cached stores ----------------
__global__ __launch_bounds__(256) void k_main(
    const float* __restrict__ pts, const int* __restrict__ faces,
    const float* __restrict__ poseoff, const int* __restrict__ mask,
    const float* __restrict__ vox_scale, const float* __restrict__ vox_offset,
    const float* __restrict__ off_full, const float* __restrict__ tfsP,
    const float* __restrict__ lbsw, const uint4* __restrict__ Gtb,
    const float* __restrict__ Stb,
    float* __restrict__ out_posed, float* __restrict__ out_T) {
    __shared__ float sx0[256], sx1[256], sx2[256];
    __shared__ float sf0[256], sf1[256], sf2[256];
    __shared__ int   scell[256];
    __shared__ unsigned short lst[256];
    __shared__ int wc[4];

    // XCD binding: round-robin dispatch puts bid%8 on XCD (bid%8).
    // b = (bid&7)>>1 -> XCD pair {2b,2b+1} only touches batch b's G-plane.
    int bid = blockIdx.x;
    int b  = (bid & 7) >> 1;
    int nc = ((bid >> 3) << 1) | (bid & 1);     // [0,512) per b, bijective
    int tid = threadIdx.x;
    int n = nc * 256 + tid;
    int i = (b << 17) | n;

    float px = pts[3 * i + 0], py = pts[3 * i + 1], pz = pts[3 * i + 2];
    int f0 = faces[3 * n + 0], f1 = faces[3 * n + 1], f2 = faces[3 * n + 2];
    const float* ob = off_full + b * COLS_;
    const float c3 = 1.f / 3.f;
    float ox = (ob[f0 * 3 + 0] + ob[f1 * 3 + 0] + ob[f2 * 3 + 0]) * c3;
    float oy = (ob[f0 * 3 + 1] + ob[f1 * 3 + 1] + ob[f2 * 3 + 1]) * c3;
    float oz = (ob[f0 * 3 + 2] + ob[f1 * 3 + 2] + ob[f2 * 3 + 2]) * c3;
    sx0[tid] = px + ox - poseoff[3 * n + 0];
    sx1[tid] = py + oy - poseoff[3 * n + 1];
    sx2[tid] = pz + oz - poseoff[3 * n + 2];

    bool isv = !(mask[i] > 0);
    if (isv) {
        float sxc = vox_scale[0], syc = vox_scale[1], szc = vox_scale[2];
        float o0 = vox_offset[0], o1 = vox_offset[1], o2 = vox_offset[2];
        float gx = fminf(fmaxf(px * sxc + o0, -1.f), 1.f);
        float gy = fminf(fmaxf(py * syc + o1, -1.f), 1.f);
        float gz = fminf(fmaxf(pz * szc + o2, -1.f), 1.f);
        float tx = (gx + 1.f) * 0.5f * (D_ - 1);
        float ty = (gy + 1.f) * 0.5f * (D_ - 1);
        float tz = (gz + 1.f) * 0.5f * (D_ - 1);
        int ix = (int)floorf(tx); if (ix > D_ - 2) ix = D_ - 2; if (ix < 0) ix = 0;
        int iy = (int)floorf(ty); if (iy > D_ - 2) iy = D_ - 2; if (iy < 0) iy = 0;
        int iz = (int)floorf(tz); if (iz > D_ - 2) iz = D_ - 2; if (iz < 0) iz = 0;
        sf0[tid] = tx - ix;
        sf1[tid] = ty - iy;
        sf2[tid] = tz - iz;
        scell[tid] = (ix * D_ + iy) * D_ + iz;
    }

    unsigned long long bal = __ballot(isv);
    int lane = tid & 63, wid = tid >> 6;
    if (lane == 0) wc[wid] = __popcll(bal);
    __syncthreads();
    int pre = 0;
#pragma unroll
    for (int k = 0; k < 4; ++k) pre += (k < wid) ? wc[k] : 0;
    int tot = wc[0] + wc[1] + wc[2] + wc[3];
    unsigned long long lt = ((unsigned long long)1 << lane) - 1ull;
    int vbefore = pre + __popcll(bal & lt);       // voxel threads before me
    int pos = isv ? vbefore : (tot + (tid - vbefore));
    lst[pos] = (unsigned short)tid;
    __syncthreads();

    int slot = lst[tid];
    float x0 = sx0[slot], x1 = sx1[slot], x2 = sx2[slot];
    int ii = (b << 17) | (nc * 256 + slot);

    float T[16];
#pragma unroll
    for (int r = 0; r < 16; ++r) T[r] = 0.f;
    float wsum = 0.f;

    if (tid < tot) {
        // voxel path: 8-corner blend of precomputed per-vertex transforms
        float fx = sf0[slot], fy = sf1[slot], fz = sf2[slot];
        int cell = scell[slot];
        const uint4* Gb = Gtb + (size_t)b * D3_ * 2;
#pragma unroll
        for (int cc = 0; cc < 4; ++cc) {
            int fid = cell + ((cc & 2) ? D_ * D_ : 0) + ((cc & 1) ? D_ : 0);
            float wxy = ((cc & 2) ? fx : 1.f - fx) * ((cc & 1) ? fy : 1.f - fy);
            float w0 = wxy * (1.f - fz);
            float w1 = wxy * fz;
            const uint4* R = Gb + (size_t)fid * 2;   // 64B: rows fid, fid+1
            uint4 q0 = R[0], q1 = R[1], q2 = R[2], q3 = R[3];
            wsum += w0 * Stb[fid] + w1 * Stb[fid + 1];
            ACC8(0, q0, q2)
            ACC8(8, q1, q3)
        }
    } else {
        // lbsw path: f32 direct, 13 dwordx4 (4B-aligned) + 3 dwords in flight
        int n2 = nc * 256 + slot;
        const float* lw = lbsw + (size_t)n2 * J_;
        f4a q[13];
#pragma unroll
        for (int k = 0; k < 13; ++k)
            q[k] = *(const f4a*)(lw + 4 * k);
        float w52 = lw[52], w53 = lw[53], w54 = lw[54];
        const float* tb = tfsP + b * (JP_ * 16);   // uniform -> s_load
#pragma unroll
        for (int k = 0; k < 13; ++k) {
#pragma unroll
            for (int m = 0; m < 4; ++m) {
                float w = q[k][m];
                wsum += w;
                const float* tr = tb + (k * 4 + m) * 16;
#pragma unroll
                for (int r = 0; r < 16; ++r) T[r] += w * tr[r];
            }
        }
        float wt[3] = { w52, w53, w54 };
#pragma unroll
        for (int m = 0; m < 3; ++m) {
            float w = wt[m];
            wsum += w;
            const float* tr = tb + (52 + m) * 16;
#pragma unroll
            for (int r = 0; r < 16; ++r) T[r] += w * tr[r];
        }
    }

    float inv = 1.f / fmaxf(wsum, 1e-8f);
    float t[16];
#pragma unroll
    for (int r = 0; r < 16; ++r) t[r] = T[r] * inv;
    // regular cached stores: block covers a contiguous region; L2 write-back
    // evicts full lines (NT partial-line amplification was 96MB vs 40 ideal)
    out_posed[3 * ii + 0] = t[0] * x0 + t[1] * x1 + t[2] * x2 + t[3];
    out_posed[3 * ii + 1] = t[4] * x0 + t[5] * x1 + t[6] * x2 + t[7];
    out_posed[3 * ii + 2] = t[8] * x0 + t[9] * x1 + t[10] * x2 + t[11];
    float4* to = (float4*)(out_T + (size_t)ii * 16);
    to[0] = make_float4(t[0], t[1], t[2], t[3]);
    to[1] = make_float4(t[4], t[5], t[6], t[7]);
    to[2] = make_float4(t[8], t[9], t[10], t[11]);
    to[3] = make_float4(t[12], t[13], t[14], t[15]);
}

extern "C" void kernel_launch(void* const* d_in, const int* in_sizes, int n_in,
                              void* d_out, int out_size, void* d_ws, size_t ws_size,
                              hipStream_t stream) {
    const float* pts      = (const float*)d_in[0];
    const float* betas    = (const float*)d_in[1];
    const float* pf       = (const float*)d_in[2];
    const float* spdir    = (const float*)d_in[3];
    const float* podir    = (const float*)d_in[4];
    const int*   faces    = (const int*)d_in[5];
    const float* tfs_A    = (const float*)d_in[6];
    const float* tfs_inv  = (const float*)d_in[7];
    const float* poseoff  = (const float*)d_in[8];
    const float* lbsw     = (const float*)d_in[9];
    const float* vox      = (const float*)d_in[10];
    const float* vscale   = (const float*)d_in[11];
    const float* voffset  = (const float*)d_in[12];
    const int*   mask     = (const int*)d_in[13];

    // workspace layout (256B-aligned)
    char* w = (char*)d_ws;
    uint4* Gtb      = (uint4*)w;                       // 33,554,432 B
    float* Stb      = (float*)(w + 33554432);          //  1,048,576 B
    float* off_full = (float*)(w + 34603008);          //    516,096 B (padded)
    float* tfsP     = (float*)(w + 35119104);          //     14,336 B
    // total: 35,133,440 B

    float* out_posed = (float*)d_out;
    float* out_T     = out_posed + (size_t)B_ * N_ * 3;

    k_tfs<<<14, 256, 0, stream>>>(tfs_A, tfs_inv, tfsP);
    k_prelude<<<GZ_ + OZ_, 256, 0, stream>>>(
        vox, tfsP, Gtb, Stb, pf, podir, betas, spdir, off_full);
    k_main<<<2048, 256, 0, stream>>>(pts, faces, poseoff, mask, vscale,
                                     voffset, off_full, tfsP, lbsw, Gtb, Stb,
                                     out_posed, out_T);
}

// Round 5
// 293.698 us; speedup vs baseline: 1.2240x; 1.2240x over previous
//
#include <hip/hip_runtime.h>

#define B_  4
#define N_  131072
#define J_  55
#define JP_ 56        // padded J (pad entries are zero)
#define D_  64
#define D3_ 262144    // 64^3
#define PF_ 486
#define COLS_ 31425   // M*3

// prelude zone sizes (blocks)
#define GZ_ 4096      // G-blend zone: (D3_/256) * B_  (one batch per block)
#define OZ_ 123       // off_pose zone: one block per 256 cols, full depth

#define BL16(u) __uint_as_float((u) << 16)
#define BH16(u) __uint_as_float((u) & 0xffff0000u)

// 16B vector with only 4B alignment guarantee (lbsw rows are 220B apart)
typedef float f4a __attribute__((ext_vector_type(4), aligned(4)));

__device__ __forceinline__ unsigned short f2bf(float v) {
    unsigned u = __float_as_uint(v);
    u += 0x7fffu + ((u >> 16) & 1u);   // round-to-nearest-even
    return (unsigned short)(u >> 16);
}

// ---------------- tfs = A @ A_inv, padded to JP_ joints --------------------
__global__ __launch_bounds__(256) void k_tfs(const float* __restrict__ A,
                                             const float* __restrict__ Ainv,
                                             float* __restrict__ tfsP) {
    int tid = blockIdx.x * 256 + threadIdx.x;
    if (tid >= B_ * JP_ * 16) return;
    int rc = tid & 15;
    int jb = tid >> 4;
    int j = jb % JP_;
    int b = jb / JP_;
    float v = 0.f;
    if (j < J_) {
        int r = rc >> 2, c = rc & 3;
#pragma unroll
        for (int k = 0; k < 4; ++k)
            v += A[((b * J_ + j) * 4 + r) * 4 + k] * Ainv[(j * 4 + k) * 4 + c];
    }
    tfsP[tid] = v;
}

// ------ k_prelude: two independent zones overlap on the GPU ----------------
// zone G  [0, GZ_):        G[b][v][16] bf16 + S[v] f32 (trilerp linearity)
//                          one (batch, 256-vertex chunk) per block: g[16]
//                          accumulator, j double-buffered -> ~50 VGPR, no
//                          spill (r4's g[4][16]+wv[55] spilled at 96 VGPR).
//                          vox re-read per b is L3-resident (57.7MB << 256MB).
// zone O  [GZ_, GZ_+OZ_):  off_full = betas@spdir + pf@podir (plain stores)
__global__ __launch_bounds__(256) void k_prelude(
    const float* __restrict__ vox, const float* __restrict__ tfsP,
    uint4* __restrict__ Gtb, float* __restrict__ Stb,
    const float* __restrict__ pf, const float* __restrict__ podir,
    const float* __restrict__ betas, const float* __restrict__ spdir,
    float* __restrict__ off_full) {
    int bx = blockIdx.x;
    int tid = threadIdx.x;

    if (bx < GZ_) {
        // XCD binding matches k_main: batch b owns XCD pair {2b, 2b+1},
        // so G[b] is written through the L2s that k_main reads it from.
        int b = (bx & 7) >> 1;
        int chunk = ((bx >> 3) << 1) | (bx & 1);   // [0,1024) per b
        int v = chunk * 256 + tid;
        float g[16];
#pragma unroll
        for (int r = 0; r < 16; ++r) g[r] = 0.f;
        float s = 0.f;
        const float* tb = tfsP + b * (JP_ * 16);   // uniform -> s_load
        float wa[11], wb[11];
#pragma unroll
        for (int k = 0; k < 11; ++k) wa[k] = vox[(size_t)k * D3_ + v];
        for (int j0 = 0; j0 < J_; j0 += 11) {
            if (j0 + 11 < J_) {
#pragma unroll
                for (int k = 0; k < 11; ++k)
                    wb[k] = vox[(size_t)(j0 + 11 + k) * D3_ + v];
            }
#pragma unroll
            for (int k = 0; k < 11; ++k) {
                float w = wa[k];
                s += w;
                const float* tr = tb + (j0 + k) * 16;
#pragma unroll
                for (int r = 0; r < 16; ++r) g[r] += w * tr[r];
            }
#pragma unroll
            for (int k = 0; k < 11; ++k) wa[k] = wb[k];
        }
        if (b == 0) Stb[v] = s;                    // batch-independent
        unsigned gw[8];
#pragma unroll
        for (int k = 0; k < 8; ++k)
            gw[k] = (unsigned)f2bf(g[2 * k]) |
                    ((unsigned)f2bf(g[2 * k + 1]) << 16);
        uint4* gp = Gtb + ((size_t)b * D3_ + v) * 2;
        gp[0] = make_uint4(gw[0], gw[1], gw[2], gw[3]);
        gp[1] = make_uint4(gw[4], gw[5], gw[6], gw[7]);
    } else {
        // ---- off_pose zone: full 486 depth, 16 loads in flight, no atomics
        int col = (bx - GZ_) * 256 + tid;
        if (col >= COLS_) return;
        float a0 = 0.f, a1 = 0.f, a2 = 0.f, a3 = 0.f;
        {   // shape blend term
            float sp[10];
#pragma unroll
            for (int l = 0; l < 10; ++l) sp[l] = spdir[col * 10 + l];
#pragma unroll
            for (int l = 0; l < 10; ++l) {
                a0 += betas[0 * 10 + l] * sp[l];
                a1 += betas[1 * 10 + l] * sp[l];
                a2 += betas[2 * 10 + l] * sp[l];
                a3 += betas[3 * 10 + l] * sp[l];
            }
        }
        int p = 0;
        for (; p + 16 <= PF_; p += 16) {
            float v16[16];
#pragma unroll
            for (int k = 0; k < 16; ++k)
                v16[k] = podir[(size_t)(p + k) * COLS_ + col];
#pragma unroll
            for (int k = 0; k < 16; ++k) {
                a0 += pf[0 * PF_ + p + k] * v16[k];
                a1 += pf[1 * PF_ + p + k] * v16[k];
                a2 += pf[2 * PF_ + p + k] * v16[k];
                a3 += pf[3 * PF_ + p + k] * v16[k];
            }
        }
        for (; p < PF_; ++p) {         // tail 486 - 480 = 6
            float v = podir[(size_t)p * COLS_ + col];
            a0 += pf[0 * PF_ + p] * v;
            a1 += pf[1 * PF_ + p] * v;
            a2 += pf[2 * PF_ + p] * v;
            a3 += pf[3 * PF_ + p] * v;
        }
        off_full[0 * COLS_ + col] = a0;
        off_full[1 * COLS_ + col] = a1;
        off_full[2 * COLS_ + col] = a2;
        off_full[3 * COLS_ + col] = a3;
    }
}

// accumulate 8 T-entries from two adjacent-corner G rows (bf16-packed)
#define ACC8(Toff, qa, qb)                                 \
    T[Toff + 0] += w0 * BL16(qa.x) + w1 * BL16(qb.x);      \
    T[Toff + 1] += w0 * BH16(qa.x) + w1 * BH16(qb.x);      \
    T[Toff + 2] += w0 * BL16(qa.y) + w1 * BL16(qb.y);      \
    T[Toff + 3] += w0 * BH16(qa.y) + w1 * BH16(qb.y);      \
    T[Toff + 4] += w0 * BL16(qa.z) + w1 * BL16(qb.z);      \
    T[Toff + 5] += w0 * BH16(qa.z) + w1 * BH16(qb.z);      \
    T[Toff + 6] += w0 * BL16(qa.w) + w1 * BL16(qb.w);      \
    T[Toff + 7] += w0 * BH16(qa.w) + w1 * BH16(qb.w);

// ------- fused main pass: compaction; regular cached stores ----------------
__global__ __launch_bounds__(256) void k_main(
    const float* __restrict__ pts, const int* __restrict__ faces,
    const float* __restrict__ poseoff, const int* __restrict__ mask,
    const float* __restrict__ vox_scale, const float* __restrict__ vox_offset,
    const float* __restrict__ off_full, const float* __restrict__ tfsP,
    const float* __restrict__ lbsw, const uint4* __restrict__ Gtb,
    const float* __restrict__ Stb,
    float* __restrict__ out_posed, float* __restrict__ out_T) {
    __shared__ float sx0[256], sx1[256], sx2[256];
    __shared__ float sf0[256], sf1[256], sf2[256];
    __shared__ int   scell[256];
    __shared__ unsigned short lst[256];
    __shared__ int wc[4];

    // XCD binding: round-robin dispatch puts bid%8 on XCD (bid%8).
    // b = (bid&7)>>1 -> XCD pair {2b,2b+1} only touches batch b's G-plane.
    int bid = blockIdx.x;
    int b  = (bid & 7) >> 1;
    int nc = ((bid >> 3) << 1) | (bid & 1);     // [0,512) per b, bijective
    int tid = threadIdx.x;
    int n = nc * 256 + tid;
    int i = (b << 17) | n;

    float px = pts[3 * i + 0], py = pts[3 * i + 1], pz = pts[3 * i + 2];
    int f0 = faces[3 * n + 0], f1 = faces[3 * n + 1], f2 = faces[3 * n + 2];
    const float* ob = off_full + b * COLS_;
    const float c3 = 1.f / 3.f;
    float ox = (ob[f0 * 3 + 0] + ob[f1 * 3 + 0] + ob[f2 * 3 + 0]) * c3;
    float oy = (ob[f0 * 3 + 1] + ob[f1 * 3 + 1] + ob[f2 * 3 + 1]) * c3;
    float oz = (ob[f0 * 3 + 2] + ob[f1 * 3 + 2] + ob[f2 * 3 + 2]) * c3;
    sx0[tid] = px + ox - poseoff[3 * n + 0];
    sx1[tid] = py + oy - poseoff[3 * n + 1];
    sx2[tid] = pz + oz - poseoff[3 * n + 2];

    bool isv = !(mask[i] > 0);
    if (isv) {
        float sxc = vox_scale[0], syc = vox_scale[1], szc = vox_scale[2];
        float o0 = vox_offset[0], o1 = vox_offset[1], o2 = vox_offset[2];
        float gx = fminf(fmaxf(px * sxc + o0, -1.f), 1.f);
        float gy = fminf(fmaxf(py * syc + o1, -1.f), 1.f);
        float gz = fminf(fmaxf(pz * szc + o2, -1.f), 1.f);
        float tx = (gx + 1.f) * 0.5f * (D_ - 1);
        float ty = (gy + 1.f) * 0.5f * (D_ - 1);
        float tz = (gz + 1.f) * 0.5f * (D_ - 1);
        int ix = (int)floorf(tx); if (ix > D_ - 2) ix = D_ - 2; if (ix < 0) ix = 0;
        int iy = (int)floorf(ty); if (iy > D_ - 2) iy = D_ - 2; if (iy < 0) iy = 0;
        int iz = (int)floorf(tz); if (iz > D_ - 2) iz = D_ - 2; if (iz < 0) iz = 0;
        sf0[tid] = tx - ix;
        sf1[tid] = ty - iy;
        sf2[tid] = tz - iz;
        scell[tid] = (ix * D_ + iy) * D_ + iz;
    }

    unsigned long long bal = __ballot(isv);
    int lane = tid & 63, wid = tid >> 6;
    if (lane == 0) wc[wid] = __popcll(bal);
    __syncthreads();
    int pre = 0;
#pragma unroll
    for (int k = 0; k < 4; ++k) pre += (k < wid) ? wc[k] : 0;
    int tot = wc[0] + wc[1] + wc[2] + wc[3];
    unsigned long long lt = ((unsigned long long)1 << lane) - 1ull;
    int vbefore = pre + __popcll(bal & lt);       // voxel threads before me
    int pos = isv ? vbefore : (tot + (tid - vbefore));
    lst[pos] = (unsigned short)tid;
    __syncthreads();

    int slot = lst[tid];
    float x0 = sx0[slot], x1 = sx1[slot], x2 = sx2[slot];
    int ii = (b << 17) | (nc * 256 + slot);

    float T[16];
#pragma unroll
    for (int r = 0; r < 16; ++r) T[r] = 0.f;
    float wsum = 0.f;

    if (tid < tot) {
        // voxel path: 8-corner blend of precomputed per-vertex transforms
        float fx = sf0[slot], fy = sf1[slot], fz = sf2[slot];
        int cell = scell[slot];
        const uint4* Gb = Gtb + (size_t)b * D3_ * 2;
#pragma unroll
        for (int cc = 0; cc < 4; ++cc) {
            int fid = cell + ((cc & 2) ? D_ * D_ : 0) + ((cc & 1) ? D_ : 0);
            float wxy = ((cc & 2) ? fx : 1.f - fx) * ((cc & 1) ? fy : 1.f - fy);
            float w0 = wxy * (1.f - fz);
            float w1 = wxy * fz;
            const uint4* R = Gb + (size_t)fid * 2;   // 64B: rows fid, fid+1
            uint4 q0 = R[0], q1 = R[1], q2 = R[2], q3 = R[3];
            wsum += w0 * Stb[fid] + w1 * Stb[fid + 1];
            ACC8(0, q0, q2)
            ACC8(8, q1, q3)
        }
    } else {
        // lbsw path: f32 direct, 13 dwordx4 (4B-aligned) + 3 dwords in flight
        int n2 = nc * 256 + slot;
        const float* lw = lbsw + (size_t)n2 * J_;
        f4a q[13];
#pragma unroll
        for (int k = 0; k < 13; ++k)
            q[k] = *(const f4a*)(lw + 4 * k);
        float w52 = lw[52], w53 = lw[53], w54 = lw[54];
        const float* tb = tfsP + b * (JP_ * 16);   // uniform -> s_load
#pragma unroll
        for (int k = 0; k < 13; ++k) {
#pragma unroll
            for (int m = 0; m < 4; ++m) {
                float w = q[k][m];
                wsum += w;
                const float* tr = tb + (k * 4 + m) * 16;
#pragma unroll
                for (int r = 0; r < 16; ++r) T[r] += w * tr[r];
            }
        }
        float wt[3] = { w52, w53, w54 };
#pragma unroll
        for (int m = 0; m < 3; ++m) {
            float w = wt[m];
            wsum += w;
            const float* tr = tb + (52 + m) * 16;
#pragma unroll
            for (int r = 0; r < 16; ++r) T[r] += w * tr[r];
        }
    }

    float inv = 1.f / fmaxf(wsum, 1e-8f);
    float t[16];
#pragma unroll
    for (int r = 0; r < 16; ++r) t[r] = T[r] * inv;
    // regular cached stores: block covers a contiguous region; L2 write-back
    // evicts full lines
    out_posed[3 * ii + 0] = t[0] * x0 + t[1] * x1 + t[2] * x2 + t[3];
    out_posed[3 * ii + 1] = t[4] * x0 + t[5] * x1 + t[6] * x2 + t[7];
    out_posed[3 * ii + 2] = t[8] * x0 + t[9] * x1 + t[10] * x2 + t[11];
    float4* to = (float4*)(out_T + (size_t)ii * 16);
    to[0] = make_float4(t[0], t[1], t[2], t[3]);
    to[1] = make_float4(t[4], t[5], t[6], t[7]);
    to[2] = make_float4(t[8], t[9], t[10], t[11]);
    to[3] = make_float4(t[12], t[13], t[14], t[15]);
}

extern "C" void kernel_launch(void* const* d_in, const int* in_sizes, int n_in,
                              void* d_out, int out_size, void* d_ws, size_t ws_size,
                              hipStream_t stream) {
    const float* pts      = (const float*)d_in[0];
    const float* betas    = (const float*)d_in[1];
    const float* pf       = (const float*)d_in[2];
    const float* spdir    = (const float*)d_in[3];
    const float* podir    = (const float*)d_in[4];
    const int*   faces    = (const int*)d_in[5];
    const float* tfs_A    = (const float*)d_in[6];
    const float* tfs_inv  = (const float*)d_in[7];
    const float* poseoff  = (const float*)d_in[8];
    const float* lbsw     = (const float*)d_in[9];
    const float* vox      = (const float*)d_in[10];
    const float* vscale   = (const float*)d_in[11];
    const float* voffset  = (const float*)d_in[12];
    const int*   mask     = (const int*)d_in[13];

    // workspace layout (256B-aligned)
    char* w = (char*)d_ws;
    uint4* Gtb      = (uint4*)w;                       // 33,554,432 B
    float* Stb      = (float*)(w + 33554432);          //  1,048,576 B
    float* off_full = (float*)(w + 34603008);          //    516,096 B (padded)
    float* tfsP     = (float*)(w + 35119104);          //     14,336 B
    // total: 35,133,440 B

    float* out_posed = (float*)d_out;
    float* out_T     = out_posed + (size_t)B_ * N_ * 3;

    k_tfs<<<14, 256, 0, stream>>>(tfs_A, tfs_inv, tfsP);
    k_prelude<<<GZ_ + OZ_, 256, 0, stream>>>(
        vox, tfsP, Gtb, Stb, pf, podir, betas, spdir, off_full);
    k_main<<<2048, 256, 0, stream>>>(pts, faces, poseoff, mask, vscale,
                                     voffset, off_full, tfsP, lbsw, Gtb, Stb,
                                     out_posed, out_T);
}